// Round 1
// baseline (2266.804 us; speedup 1.0000x reference)
//
#include <hip/hip_runtime.h>
#include <hip/hip_bf16.h>

using short8  = __attribute__((ext_vector_type(8))) short;
using short4v = __attribute__((ext_vector_type(4))) short;
using fx4     = __attribute__((ext_vector_type(4))) float;

#define NB 8
#define CDIM 256
#define HH 128
#define NPIX 16384
#define NG_ELEMS 131072.0f

__device__ __forceinline__ float bf2f(short s) {
    union { unsigned u; float f; } c; c.u = ((unsigned)(unsigned short)s) << 16; return c.f;
}
__device__ __forceinline__ short f2bf(float f) {
    union { float f; unsigned u; } c; c.f = f;
    unsigned u = c.u;
    u += 0x7FFFu + ((u >> 16) & 1u);
    return (short)(u >> 16);
}
// packed RTNE fp32x2 -> bf16x2 (v_cvt_pk_bf16_f32 on gfx950)
__device__ __forceinline__ short2 f2bf2(float a, float b) {
    __hip_bfloat162 h = __float22bfloat162_rn(make_float2(a, b));
    union { __hip_bfloat162 b; short2 s; } c; c.b = h; return c.s;
}

// ---------------- Kernel W: wq/wk fp32 -> bf16 in MFMA fragment order ----------------
// WB[t][kc(8)][ntile(16)][lane(64)][8el]; lane=(quad*16+lr): value W[ntile*16+lr][kc*32+quad*8+e]
__global__ __launch_bounds__(256) void kW(const float* __restrict__ wq,
                                          const float* __restrict__ wk,
                                          short* __restrict__ WB) {
    int kc = blockIdx.x;      // 0..7
    int t  = blockIdx.y;      // 0..1
    const float* W = t ? wk : wq;
    int tid = threadIdx.x;
    int ntile = tid >> 4, lr = tid & 15;
    int n = ntile * 16 + lr;
#pragma unroll
    for (int quad = 0; quad < 4; ++quad) {
        const float* p = W + (size_t)n * CDIM + kc * 32 + quad * 8;
        fx4 v0 = *(const fx4*)p;
        fx4 v1 = *(const fx4*)(p + 4);
        union { short8 v; short2 h[4]; } s;
        s.h[0] = f2bf2(v0[0], v0[1]);
        s.h[1] = f2bf2(v0[2], v0[3]);
        s.h[2] = f2bf2(v1[0], v1[1]);
        s.h[3] = f2bf2(v1[2], v1[3]);
        *(short8*)(WB + ((((size_t)t * 8 + kc) * 16 + ntile) * 64 + quad * 16 + lr) * 8) = s.v;
    }
}

// ---------------- Kernel G: barrier-free streaming GEMM + group stats ------------------
// v2: A=W (L2-hot frags), B=X (direct gather, double-buffered register prefetch).
// D-layout: lane holds 4 consecutive OUT channels for one pixel -> short4 stores.
// Block = 64 pixels x 256 out; 4 waves = 4 out-quarters sharing the same gathers (L1).

#define GATHER(BUF, KCV) do {                                                      \
    const float* xp_ = X + (size_t)((KCV) * 32 + quad * 8) * NPIX + m0 + lr;       \
    _Pragma("unroll") for (int pt_ = 0; pt_ < 4; ++pt_)                            \
    _Pragma("unroll") for (int e_ = 0; e_ < 8; ++e_)                               \
        BUF[pt_ * 8 + e_] = xp_[(size_t)e_ * NPIX + pt_ * 16];                     \
} while (0)

#define STEP(CUR, NXT, KCV, PF) do {                                               \
    short8 af_[4];                                                                 \
    const short* wb_ = WBt + (((size_t)(KCV) * 16 + w * 4) * 64 + l) * 8;          \
    _Pragma("unroll") for (int m_ = 0; m_ < 4; ++m_)                               \
        af_[m_] = *(const short8*)(wb_ + (size_t)m_ * 64 * 8);                     \
    if (PF) { GATHER(NXT, (KCV) + 1); }                                            \
    short8 bf_[4];                                                                 \
    _Pragma("unroll") for (int pt_ = 0; pt_ < 4; ++pt_) {                          \
        union { short8 v; short2 h[4]; } s_;                                       \
        _Pragma("unroll") for (int j_ = 0; j_ < 4; ++j_)                           \
            s_.h[j_] = f2bf2(CUR[pt_ * 8 + 2 * j_], CUR[pt_ * 8 + 2 * j_ + 1]);    \
        bf_[pt_] = s_.v;                                                           \
    }                                                                              \
    _Pragma("unroll") for (int m_ = 0; m_ < 4; ++m_)                               \
    _Pragma("unroll") for (int pt_ = 0; pt_ < 4; ++pt_)                            \
        acc[m_][pt_] = __builtin_amdgcn_mfma_f32_16x16x32_bf16(af_[m_], bf_[pt_],  \
                                                               acc[m_][pt_], 0, 0, 0); \
} while (0)

__global__ __launch_bounds__(256, 2) void kG(const float* __restrict__ xlo,
                                             const float* __restrict__ xhi,
                                             const short* __restrict__ WB,
                                             short* __restrict__ qt,
                                             short* __restrict__ kt,
                                             float* __restrict__ stats) {
    int m0 = blockIdx.x * 64;                  // 64 pixels per block
    int zy = blockIdx.y;                       // 0..15
    int b = zy >> 1, t = zy & 1;
    const float* X = (t ? xhi : xlo) + (size_t)b * CDIM * NPIX;
    const short* WBt = WB + (size_t)t * 8 * 16 * 64 * 8;
    short* OUT = (t ? kt : qt) + (size_t)b * NPIX * CDIM;
    int tid = threadIdx.x;
    int w = tid >> 6, l = tid & 63, lr = l & 15, quad = l >> 4;

    fx4 acc[4][4];                             // [out-tile m][pix-tile n]
#pragma unroll
    for (int m = 0; m < 4; ++m)
#pragma unroll
        for (int n = 0; n < 4; ++n) { acc[m][n][0]=0.f; acc[m][n][1]=0.f; acc[m][n][2]=0.f; acc[m][n][3]=0.f; }

    float pfA[32], pfB[32];                    // fp32 gather staging, [pt*8+e], static-indexed

    GATHER(pfA, 0);
    STEP(pfA, pfB, 0, 1);
    STEP(pfB, pfA, 1, 1);
    STEP(pfA, pfB, 2, 1);
    STEP(pfB, pfA, 3, 1);
    STEP(pfA, pfB, 4, 1);
    STEP(pfB, pfA, 5, 1);
    STEP(pfA, pfB, 6, 1);
    STEP(pfB, pfA, 7, 0);

    // group stats: lane holds o = w*64 + m*16 + quad*4 + r at pixel n*16+lr.
    // In-lane sum over pixel-tiles, then 4-round shfl over lr, one writer per 16 lanes.
    {
        float s[4][4], ss[4][4];
#pragma unroll
        for (int m = 0; m < 4; ++m)
#pragma unroll
            for (int r = 0; r < 4; ++r) {
                float a0 = acc[m][0][r], a1 = acc[m][1][r], a2 = acc[m][2][r], a3 = acc[m][3][r];
                s[m][r]  = (a0 + a1) + (a2 + a3);
                ss[m][r] = (a0 * a0 + a1 * a1) + (a2 * a2 + a3 * a3);
            }
#pragma unroll
        for (int m = 0; m < 4; ++m)
#pragma unroll
            for (int r = 0; r < 4; ++r) {
                float sv = s[m][r], sq = ss[m][r];
                sv += __shfl_xor(sv, 1);  sq += __shfl_xor(sq, 1);
                sv += __shfl_xor(sv, 2);  sq += __shfl_xor(sq, 2);
                sv += __shfl_xor(sv, 4);  sq += __shfl_xor(sq, 4);
                sv += __shfl_xor(sv, 8);  sq += __shfl_xor(sq, 8);
                if (lr == 0) {
                    int o = w * 64 + m * 16 + quad * 4 + r;
                    int g = o >> 3;
                    float* st = stats + ((size_t)(t * NB + b) * 32 + g) * 2;
                    atomicAdd(st, sv);
                    atomicAdd(st + 1, sq);
                }
            }
    }

    // store bf16 [pix][o]: 8-byte short4 per (m,n)
#pragma unroll
    for (int n = 0; n < 4; ++n) {
        int pix = m0 + n * 16 + lr;
        short* op = OUT + (size_t)pix * CDIM + w * 64 + quad * 4;
#pragma unroll
        for (int m = 0; m < 4; ++m) {
            short2 p0 = f2bf2(acc[m][n][0], acc[m][n][1]);
            short2 p1 = f2bf2(acc[m][n][2], acc[m][n][3]);
            short4v v; v[0] = p0.x; v[1] = p0.y; v[2] = p1.x; v[3] = p1.y;
            *(short4v*)(op + m * 16) = v;
        }
    }
}

// ---------------- Kernel S: stats -> per-(tensor,b,o) scale/shift ----------------------
__global__ __launch_bounds__(256) void kS(const float* __restrict__ stats,
                                          const float* __restrict__ gq,
                                          const float* __restrict__ bq,
                                          const float* __restrict__ gk,
                                          const float* __restrict__ bk,
                                          float* __restrict__ scale,
                                          float* __restrict__ shift) {
    int id = blockIdx.x * 256 + threadIdx.x;   // 0..4095
    int t = id >> 11, b = (id >> 8) & 7, o = id & 255;
    int g = o >> 3;
    const float* st = stats + ((size_t)(t * NB + b) * 32 + g) * 2;
    float mean = st[0] * (1.0f / NG_ELEMS);
    float var  = st[1] * (1.0f / NG_ELEMS) - mean * mean;
    float rstd = rsqrtf(var + 1e-5f);
    float gamma = (t ? gk : gq)[o];
    float beta  = (t ? bk : bq)[o];
    float sc = gamma * rstd;
    scale[id] = sc;
    shift[id] = beta - mean * sc;
}

// ---------------- Kernel A: windowed attention + fp32 residual/output ------------------
__global__ __launch_bounds__(256) void kA(const short* __restrict__ qt,
                                          const short* __restrict__ kt,
                                          const float* __restrict__ scale,
                                          const float* __restrict__ shift,
                                          const float* __restrict__ xlo,
                                          float* __restrict__ outp) {
    __shared__ short Ks[64 * 264];     // normalized K window [j][c], pad 8
    __shared__ float SsF[64 * 68];     // scores fp32; later reused as Os (short, stride 136)
    __shared__ short Ps[64 * 72];      // softmax probs bf16 [i][j], pad 8
    short* Os = (short*)SsF;

    int blk = blockIdx.x;              // 0..2047
    int b = blk >> 8, wh = (blk >> 4) & 15, ww = blk & 15;
    int tid = threadIdx.x;
    int w = tid >> 6, l = tid & 63, lr = l & 15, quad = l >> 4;

    const float* sq = scale + (size_t)b * CDIM;
    const float* zq = shift + (size_t)b * CDIM;
    const float* sk = scale + (size_t)(NB + b) * CDIM;
    const float* zk = shift + (size_t)(NB + b) * CDIM;

    // build normalized K window in LDS
    {
        int oct = tid & 31;
        int j00 = tid >> 5;
        float skv[8], zkv[8];
#pragma unroll
        for (int e = 0; e < 8; ++e) { skv[e] = sk[oct * 8 + e]; zkv[e] = zk[oct * 8 + e]; }
#pragma unroll
        for (int it = 0; it < 8; ++it) {
            int j = j00 + it * 8;
            int pix = (wh * 8 + (j >> 3)) * HH + ww * 8 + (j & 7);
            short8 kv = *(const short8*)(kt + ((size_t)b * NPIX + pix) * CDIM + oct * 8);
            short8 nv;
#pragma unroll
            for (int e = 0; e < 8; ++e) nv[e] = f2bf(bf2f(kv[e]) * skv[e] + zkv[e]);
            *(short8*)(&Ks[j * 264 + oct * 8]) = nv;
        }
    }
    __syncthreads();

    // S = Qn @ Kn^T / 16 ; wave w computes rows [16w,16w+16)
    {
        fx4 accS[4];
#pragma unroll
        for (int nt = 0; nt < 4; ++nt) { accS[nt][0]=0.f; accS[nt][1]=0.f; accS[nt][2]=0.f; accS[nt][3]=0.f; }
        int qi = 16 * w + lr;
        int pixq = (wh * 8 + (qi >> 3)) * HH + ww * 8 + (qi & 7);
        const short* qrow = qt + ((size_t)b * NPIX + pixq) * CDIM;
#pragma unroll
        for (int kc = 0; kc < 8; ++kc) {
            int c0 = kc * 32 + quad * 8;
            short8 qv = *(const short8*)(qrow + c0);
            short8 aq;
#pragma unroll
            for (int e = 0; e < 8; ++e) aq[e] = f2bf(bf2f(qv[e]) * sq[c0 + e] + zq[c0 + e]);
#pragma unroll
            for (int nt = 0; nt < 4; ++nt) {
                short8 bk8 = *(const short8*)(&Ks[(nt * 16 + lr) * 264 + c0]);
                accS[nt] = __builtin_amdgcn_mfma_f32_16x16x32_bf16(aq, bk8, accS[nt], 0, 0, 0);
            }
        }
#pragma unroll
        for (int nt = 0; nt < 4; ++nt)
#pragma unroll
            for (int r = 0; r < 4; ++r)
                SsF[(16 * w + quad * 4 + r) * 68 + nt * 16 + lr] = accS[nt][r] * 0.0625f;
    }
    __syncthreads();

    // softmax over rows (4 threads per row)
    {
        int row = tid >> 2, seg = tid & 3;
        float v[16];
#pragma unroll
        for (int k4 = 0; k4 < 4; ++k4) {
            fx4 t4 = *(const fx4*)(&SsF[row * 68 + seg * 16 + k4 * 4]);
            v[k4*4+0] = t4[0]; v[k4*4+1] = t4[1]; v[k4*4+2] = t4[2]; v[k4*4+3] = t4[3];
        }
        float m = v[0];
#pragma unroll
        for (int e = 1; e < 16; ++e) m = fmaxf(m, v[e]);
        m = fmaxf(m, __shfl_xor(m, 1));
        m = fmaxf(m, __shfl_xor(m, 2));
        float s = 0.f;
#pragma unroll
        for (int e = 0; e < 16; ++e) { v[e] = __expf(v[e] - m); s += v[e]; }
        s += __shfl_xor(s, 1);
        s += __shfl_xor(s, 2);
        float inv = 1.0f / s;
        short8 p0, p1;
#pragma unroll
        for (int e = 0; e < 8; ++e) { p0[e] = f2bf(v[e] * inv); p1[e] = f2bf(v[8 + e] * inv); }
        *(short8*)(&Ps[row * 72 + seg * 16]) = p0;
        *(short8*)(&Ps[row * 72 + seg * 16 + 8]) = p1;
    }
    __syncthreads();

    // O = P @ Kn ; wave w computes channels [64w, 64w+64)
    fx4 accO[4][4];
#pragma unroll
    for (int mt = 0; mt < 4; ++mt)
#pragma unroll
        for (int nt = 0; nt < 4; ++nt) { accO[mt][nt][0]=0.f; accO[mt][nt][1]=0.f; accO[mt][nt][2]=0.f; accO[mt][nt][3]=0.f; }
#pragma unroll
    for (int kc2 = 0; kc2 < 2; ++kc2) {
        int j0 = kc2 * 32 + quad * 8;
        short8 ap[4];
#pragma unroll
        for (int mt = 0; mt < 4; ++mt)
            ap[mt] = *(const short8*)(&Ps[(mt * 16 + lr) * 72 + j0]);
#pragma unroll
        for (int nt = 0; nt < 4; ++nt) {
            int c = 64 * w + nt * 16 + lr;
            short8 bk8;
#pragma unroll
            for (int jj = 0; jj < 8; ++jj) bk8[jj] = Ks[(j0 + jj) * 264 + c];
#pragma unroll
            for (int mt = 0; mt < 4; ++mt)
                accO[mt][nt] = __builtin_amdgcn_mfma_f32_16x16x32_bf16(ap[mt], bk8, accO[mt][nt], 0, 0, 0);
        }
    }

    // epilogue in two halves (Os overlays Ss region), transposed, fp32 residual + store
    int half = w >> 1;
#pragma unroll
    for (int h2 = 0; h2 < 2; ++h2) {
        __syncthreads();
        if (half == h2) {
#pragma unroll
            for (int mt = 0; mt < 4; ++mt)
#pragma unroll
                for (int nt = 0; nt < 4; ++nt) {
                    int i = mt * 16 + quad * 4;
                    int cl = 64 * w + nt * 16 + lr - 128 * h2;   // 0..127
#pragma unroll
                    for (int r = 0; r < 4; ++r)
                        Os[(i + r) * 136 + cl] = f2bf(accO[mt][nt][r]);
                }
        }
        __syncthreads();
#pragma unroll
        for (int it = 0; it < 4; ++it) {
            int id = tid + it * 256;
            int cl = id & 127, h = id >> 7;   // h 0..7
            int cg = cl + 128 * h2;
            size_t gidx = ((size_t)(b * CDIM + cg)) * NPIX + (size_t)(wh * 8 + h) * HH + ww * 8;
            fx4 x0 = *(const fx4*)(xlo + gidx);
            fx4 x1 = *(const fx4*)(xlo + gidx + 4);
            fx4 r0, r1;
#pragma unroll
            for (int jj = 0; jj < 4; ++jj) {
                r0[jj] = bf2f(Os[(h * 8 + jj)     * 136 + cl]) + x0[jj];
                r1[jj] = bf2f(Os[(h * 8 + 4 + jj) * 136 + cl]) + x1[jj];
            }
            *(fx4*)(outp + gidx)     = r0;
            *(fx4*)(outp + gidx + 4) = r1;
        }
    }
}

extern "C" void kernel_launch(void* const* d_in, const int* in_sizes, int n_in,
                              void* d_out, int out_size, void* d_ws, size_t ws_size,
                              hipStream_t stream) {
    const float* xlo = (const float*)d_in[0];
    const float* xhi = (const float*)d_in[1];
    const float* wqp = (const float*)d_in[2];
    const float* wkp = (const float*)d_in[3];
    const float* gq  = (const float*)d_in[4];
    const float* bq  = (const float*)d_in[5];
    const float* gk  = (const float*)d_in[6];
    const float* bk  = (const float*)d_in[7];
    float* outp = (float*)d_out;
    char* ws = (char*)d_ws;
    size_t SZB = (size_t)NB * NPIX * CDIM * 2;   // 64 MB per bf16 tensor
    short* qt    = (short*)(ws);
    short* kt    = (short*)(ws + SZB);
    float* stats = (float*)(ws + 2 * SZB);
    float* scale = (float*)(ws + 2 * SZB + 4096);
    float* shift = (float*)(ws + 2 * SZB + 4096 + 16384);
    short* WB    = (short*)(ws + 2 * SZB + 4096 + 32768);

    hipMemsetAsync(stats, 0, 4096, stream);
    kW<<<dim3(8, 2), dim3(256), 0, stream>>>(wqp, wkp, WB);
    kG<<<dim3(256, 16), dim3(256), 0, stream>>>(xlo, xhi, WB, qt, kt, stats);
    kS<<<dim3(16), dim3(256), 0, stream>>>(stats, gq, bq, gk, bk, scale, shift);
    kA<<<dim3(2048), dim3(256), 0, stream>>>(qt, kt, scale, shift, xlo, outp);
}